// Round 1
// 665.720 us; speedup vs baseline: 1.1115x; 1.1115x over previous
//
#include <hip/hip_runtime.h>
#include <hip/hip_bf16.h>
#include <stdint.h>

// GNN_758: stacked RelGraphConv x2.  N=50000, E=1.6M, D=128, R=20.
// agg[dst] = sum_r (sum_{e in rel r -> dst} h[src]) @ W[r]; self-loop = rel 20.
// R8: occupancy rebuild of the fused layer kernel.
//  - Sb staged in bf16 (cvt moved from phase 2 to phase 1 store; identical numerics)
//  - XOR-swizzled Sb (slot16 ^= row&15): conflict-free writes AND reads, 16B aligned
//  - nc-split phase 2 (wave owns 32 output cols, loops ks=0..3): no cross-wave
//    reduction, no 33KB red scratch, acc[2] instead of acc[8]
//  - spk staging dropped (es reads are 1KB/block sequential, L1/L2 resident)
//  - self-loop moved to 5th mini-chunk -> Sb holds 5 slots (20480 B)
//  LDS 53760 -> ~23040 B: 3 -> 6-7 blocks/CU (12 -> 24-28 waves/CU).

#define NN 50000
#define NE 1600000
#define DIM 128
#define NREL 20
#define NRELP 21
#define TILE 16
#define NTILE (NN / TILE)          // 3125
#define CELLS (NN * 32)            // dst*32 + chunk*8 + rl (rl 0..4 used)
#define SCAN_EPB 2048
#define NBLK_A ((CELLS + SCAN_EPB - 1) / SCAN_EPB)   // 782
#define PACKED_ELEMS (2 * NRELP * 4 * 8 * 64 * 8)    // 688128

typedef __attribute__((ext_vector_type(8))) short short8;
typedef __attribute__((ext_vector_type(4))) float f32x4;

__device__ __forceinline__ unsigned short f32_to_bf16_raw(float f) {
  union { float f; unsigned u; } c; c.f = f;
  unsigned u = c.u;
  return (unsigned short)((u + 0x7fffu + ((u >> 16) & 1u)) >> 16);  // RNE
}
__device__ __forceinline__ float bf16_raw_to_f32(unsigned short s) {
  union { unsigned u; float f; } c; c.u = ((unsigned)s) << 16;
  return c.f;
}

// ---------------- fp32 -> bf16 (x4), nontemporal stores ----------------
__global__ void cvt_bf16_kernel(const float* __restrict__ in,
                                unsigned short* __restrict__ out, int n4) {
  int i = blockIdx.x * 256 + threadIdx.x;
  if (i < n4) {
    float4 f = ((const float4*)in)[i];
    unsigned long long p =
        (unsigned long long)f32_to_bf16_raw(f.x)
      | ((unsigned long long)f32_to_bf16_raw(f.y) << 16)
      | ((unsigned long long)f32_to_bf16_raw(f.z) << 32)
      | ((unsigned long long)f32_to_bf16_raw(f.w) << 48);
    __builtin_nontemporal_store(p, (unsigned long long*)out + i);  // clean -> L3
  }
}

// ---------------- pack W (+loop_w as rel 20) into B-fragment order ----------------
// WP flat: ((((l*21 + r)*4 + ks)*8 + nc)*64 + lane)*8  (verified R0/R1)
__global__ void pack_w_kernel(const float* __restrict__ W,
                              const float* __restrict__ loop_w,
                              unsigned short* __restrict__ WP) {
  int idx = blockIdx.x * 256 + threadIdx.x;
  if (idx >= PACKED_ELEMS) return;
  int j = idx & 7;       int t = idx >> 3;
  int lane = t & 63;     t >>= 6;
  int nc = t & 7;        t >>= 3;
  int ks = t & 3;        t >>= 2;
  int r = t % NRELP;     int l = t / NRELP;
  int k = ks * 32 + (lane >> 4) * 8 + j;
  int n = nc * 16 + (lane & 15);
  float v = (r < NREL) ? W[(((size_t)l * NREL + r) * DIM + k) * DIM + n]
                       : loop_w[((size_t)l * DIM + k) * DIM + n];
  WP[idx] = f32_to_bf16_raw(v);
}

// ---------------- global cell sort: hist -> scan(A,B,C) -> scatter ----------------
__global__ void hist_kernel(const int* __restrict__ dst, const int* __restrict__ et,
                            unsigned int* __restrict__ cnt, int n) {
  int i = blockIdx.x * 256 + threadIdx.x;
  if (i < n) {
    int e = et[i];
    atomicAdd(&cnt[dst[i] * 32 + (e / 5) * 8 + (e % 5)], 1u);
  }
}

__global__ void scanA_kernel(const unsigned int* __restrict__ cnt,
                             unsigned int* __restrict__ cofs,
                             unsigned int* __restrict__ btot) {
  __shared__ unsigned int buf[256];
  int tid = threadIdx.x;
  int base = blockIdx.x * SCAN_EPB + tid * 8;
  unsigned int v[8], p[8], s = 0;
#pragma unroll
  for (int j = 0; j < 8; ++j) {
    v[j] = (base + j < CELLS) ? cnt[base + j] : 0u;
    p[j] = s; s += v[j];
  }
  buf[tid] = s;
  __syncthreads();
  for (int d = 1; d < 256; d <<= 1) {
    unsigned int a = (tid >= d) ? buf[tid - d] : 0u;
    __syncthreads();
    buf[tid] += a;
    __syncthreads();
  }
  unsigned int excl = buf[tid] - s;
#pragma unroll
  for (int j = 0; j < 8; ++j)
    if (base + j < CELLS) cofs[base + j] = excl + p[j];
  if (tid == 255) btot[blockIdx.x] = buf[255];
}

__global__ void scanB_kernel(unsigned int* __restrict__ btot,
                             unsigned int* __restrict__ cofs) {
  __shared__ unsigned int buf[1024];
  int t = threadIdx.x;
  unsigned int v = (t < NBLK_A) ? btot[t] : 0u;
  buf[t] = v;
  __syncthreads();
  for (int d = 1; d < 1024; d <<= 1) {
    unsigned int a = (t >= d) ? buf[t - d] : 0u;
    __syncthreads();
    buf[t] += a;
    __syncthreads();
  }
  if (t < NBLK_A) btot[t] = buf[t] - v;   // exclusive
  if (t == 1023) cofs[CELLS] = buf[1023]; // = NE sentinel
}

__global__ void scanC_kernel(const unsigned int* __restrict__ btot,
                             unsigned int* __restrict__ cofs,
                             unsigned int* __restrict__ cursor) {
  int base = blockIdx.x * SCAN_EPB + threadIdx.x * 8;
  unsigned int add = btot[blockIdx.x];
#pragma unroll
  for (int j = 0; j < 8; ++j)
    if (base + j < CELLS) {
      unsigned int x = cofs[base + j] + add;
      cofs[base + j] = x;
      cursor[base + j] = x;
    }
}

__global__ void scatter_kernel(const int* __restrict__ src, const int* __restrict__ dst,
                               const int* __restrict__ et,
                               unsigned int* __restrict__ cursor,
                               unsigned short* __restrict__ es, int n) {
  int i = blockIdx.x * 256 + threadIdx.x;
  if (i < n) {
    int e = et[i];
    unsigned int pos = atomicAdd(&cursor[dst[i] * 32 + (e / 5) * 8 + (e % 5)], 1u);
    es[pos] = (unsigned short)src[i];   // N < 65536
  }
}

// ---------------- fused RGCN layer ----------------
// 3125 blocks x 256 threads (4 waves). LDS ~22.5 KB -> 6-7 blocks/CU.
__global__ __launch_bounds__(256, 6) void rgcn_layer_kernel(
    const unsigned short* __restrict__ hb,    // [N,128] bf16
    const unsigned short* __restrict__ WP,    // packed weights
    const float* __restrict__ bias,           // [128] this layer
    int layer,
    const unsigned int* __restrict__ cofs,    // [CELLS+1] cell offsets
    const unsigned short* __restrict__ es,    // [E] srcs, cell-sorted
    float* __restrict__ outf,                 // fp32 out (layer 1) or null
    unsigned short* __restrict__ outb)        // bf16 out (layer 0) or null
{
  // Sb: [16 dst rows][5 rl slots * 16 slot16], each slot16 = 8 bf16 (16B).
  // Swizzle: slot16 index ^= (row & 15) within its 16-slot rl window.
  __shared__ short8 Sb8[TILE * 80];          // 20480 B
  __shared__ unsigned int cofs_l[513];       // 2052 B

  const int tid  = threadIdx.x;
  const int lane = tid & 63;
  const int w    = tid >> 6;        // wave 0..3
  const int quad = lane >> 4;
  const int m    = lane & 15;
  const int g    = w * 4 + quad;    // 16-lane group id == owned dst_local
  const int dst_base = blockIdx.x * TILE;

  for (int i = tid; i < 513; i += 256) cofs_l[i] = cofs[blockIdx.x * 512 + i];
  __syncthreads();

  f32x4 acc[2];
  acc[0] = (f32x4){0.f, 0.f, 0.f, 0.f};
  acc[1] = (f32x4){0.f, 0.f, 0.f, 0.f};

  for (int c = 0; c < 5; ++c) {
    const int rc = (c == 4) ? 1 : 5;

    // ---- phase 1: group g owns dst g; register-accumulate each cell ----
    for (int rl = 0; rl < rc; ++rl) {
      float a0 = 0.f, a1 = 0.f, a2 = 0.f, a3 = 0.f;
      float a4 = 0.f, a5 = 0.f, a6 = 0.f, a7 = 0.f;
      if (c < 4) {
        const int idx = g * 32 + c * 8 + rl;
        const int beg = (int)cofs_l[idx];
        const int end = (int)cofs_l[idx + 1];
        for (int i = beg; i < end; ++i) {
          int src = (int)es[i];
          short8 hv = *(const short8*)(hb + (size_t)src * DIM + m * 8);
          a0 += bf16_raw_to_f32((unsigned short)hv[0]);
          a1 += bf16_raw_to_f32((unsigned short)hv[1]);
          a2 += bf16_raw_to_f32((unsigned short)hv[2]);
          a3 += bf16_raw_to_f32((unsigned short)hv[3]);
          a4 += bf16_raw_to_f32((unsigned short)hv[4]);
          a5 += bf16_raw_to_f32((unsigned short)hv[5]);
          a6 += bf16_raw_to_f32((unsigned short)hv[6]);
          a7 += bf16_raw_to_f32((unsigned short)hv[7]);
        }
      } else {
        // self-loop mini-chunk: own row (feeds rel 20 = loop_w)
        short8 hv = *(const short8*)(hb + (size_t)(dst_base + g) * DIM + m * 8);
        a0 = bf16_raw_to_f32((unsigned short)hv[0]);
        a1 = bf16_raw_to_f32((unsigned short)hv[1]);
        a2 = bf16_raw_to_f32((unsigned short)hv[2]);
        a3 = bf16_raw_to_f32((unsigned short)hv[3]);
        a4 = bf16_raw_to_f32((unsigned short)hv[4]);
        a5 = bf16_raw_to_f32((unsigned short)hv[5]);
        a6 = bf16_raw_to_f32((unsigned short)hv[6]);
        a7 = bf16_raw_to_f32((unsigned short)hv[7]);
      }
      short8 p;
      p[0] = (short)f32_to_bf16_raw(a0);
      p[1] = (short)f32_to_bf16_raw(a1);
      p[2] = (short)f32_to_bf16_raw(a2);
      p[3] = (short)f32_to_bf16_raw(a3);
      p[4] = (short)f32_to_bf16_raw(a4);
      p[5] = (short)f32_to_bf16_raw(a5);
      p[6] = (short)f32_to_bf16_raw(a6);
      p[7] = (short)f32_to_bf16_raw(a7);
      Sb8[g * 80 + ((rl * 16 + m) ^ g)] = p;   // swizzled write, conflict-free
    }
    __syncthreads();

    // ---- phase 2: nc-split. wave w owns cols [32w, 32w+32); full K via ks loop ----
    for (int rl = 0; rl < rc; ++rl) {
      const int r = (c == 4) ? (NRELP - 1) : (c * 5 + rl);
      const unsigned short* bp =
          WP + ((size_t)(layer * NRELP + r) * 4) * 4096 + (size_t)w * 1024 + lane * 8;
#pragma unroll
      for (int ks = 0; ks < 4; ++ks) {
        short8 a = Sb8[m * 80 + ((rl * 16 + ks * 4 + quad) ^ m)];  // row=m (dst)
        const unsigned short* bq = bp + (size_t)ks * 4096;
        short8 b0 = *(const short8*)bq;           // nc = 2w
        short8 b1 = *(const short8*)(bq + 512);   // nc = 2w+1
        acc[0] = __builtin_amdgcn_mfma_f32_16x16x32_bf16(a, b0, acc[0], 0, 0, 0);
        acc[1] = __builtin_amdgcn_mfma_f32_16x16x32_bf16(a, b1, acc[1], 0, 0, 0);
      }
    }
    __syncthreads();
  }

  // ---- epilogue: direct store, no cross-wave reduction needed ----
  // D layout (16x16x32): row = quad*4 + i (dst-local), col-within-16 = m.
  const int col0 = w * 32 + m;       // nc=2w tile
  const float b0 = bias[col0];
  const float b1 = bias[col0 + 16];
#pragma unroll
  for (int i = 0; i < 4; ++i) {
    const size_t row = (size_t)(dst_base + quad * 4 + i);
    float o0 = acc[0][i] + b0;
    float o1 = acc[1][i] + b1;
    if (outb) {
      outb[row * DIM + col0]      = f32_to_bf16_raw(o0);
      outb[row * DIM + col0 + 16] = f32_to_bf16_raw(o1);
    } else {
      outf[row * DIM + col0]      = o0;
      outf[row * DIM + col0 + 16] = o1;
    }
  }
}

// ---------------- launch ----------------
extern "C" void kernel_launch(void* const* d_in, const int* in_sizes, int n_in,
                              void* d_out, int out_size, void* d_ws, size_t ws_size,
                              hipStream_t stream) {
  const float* h0     = (const float*)d_in[0];
  const float* W      = (const float*)d_in[1];
  const float* loop_w = (const float*)d_in[2];
  const float* bias   = (const float*)d_in[3];
  const int* esrc     = (const int*)d_in[4];
  const int* edst     = (const int*)d_in[5];
  const int* etyp     = (const int*)d_in[6];
  float* out = (float*)d_out;

  char* ws = (char*)d_ws;
  size_t off = 0;
  auto alloc = [&](size_t bytes) -> void* {
    void* p = ws + off;
    off = (off + bytes + 255) & ~(size_t)255;
    return p;
  };
  unsigned short* hb0   = (unsigned short*)alloc((size_t)NN * DIM * 2);   // 12.8 MB
  unsigned short* hb1   = (unsigned short*)alloc((size_t)NN * DIM * 2);   // 12.8 MB
  unsigned short* WP    = (unsigned short*)alloc((size_t)PACKED_ELEMS * 2);
  unsigned int*   cnt   = (unsigned int*)alloc((size_t)CELLS * 4);        // 6.4 MB
  unsigned int*   cofs  = (unsigned int*)alloc((size_t)(CELLS + 1) * 4);  // 6.4 MB
  unsigned int*   cursor= (unsigned int*)alloc((size_t)CELLS * 4);        // 6.4 MB
  unsigned int*   btot  = (unsigned int*)alloc((size_t)NBLK_A * 4);
  unsigned short* es    = (unsigned short*)alloc((size_t)NE * 2);         // 3.2 MB

  (void)hipMemsetAsync(cnt, 0, (size_t)CELLS * 4, stream);
  hist_kernel<<<NE / 256, 256, 0, stream>>>(edst, etyp, cnt, NE);
  scanA_kernel<<<NBLK_A, 256, 0, stream>>>(cnt, cofs, btot);
  scanB_kernel<<<1, 1024, 0, stream>>>(btot, cofs);
  scanC_kernel<<<NBLK_A, 256, 0, stream>>>(btot, cofs, cursor);
  scatter_kernel<<<NE / 256, 256, 0, stream>>>(esrc, edst, etyp, cursor, es, NE);

  pack_w_kernel<<<(PACKED_ELEMS + 255) / 256, 256, 0, stream>>>(W, loop_w, WP);
  cvt_bf16_kernel<<<(NN * DIM / 4 + 255) / 256, 256, 0, stream>>>(h0, hb0, NN * DIM / 4);

  rgcn_layer_kernel<<<NTILE, 256, 0, stream>>>(hb0, WP, bias, 0, cofs, es,
                                               nullptr, hb1);
  rgcn_layer_kernel<<<NTILE, 256, 0, stream>>>(hb1, WP, bias + DIM, 1, cofs, es,
                                               out, nullptr);
}

// Round 2
// 531.091 us; speedup vs baseline: 1.3933x; 1.2535x over previous
//
#include <hip/hip_runtime.h>
#include <hip/hip_bf16.h>
#include <stdint.h>

// GNN_758: stacked RelGraphConv x2.  N=50000, E=1.6M, D=128, R=20.
// agg[dst] = sum_r (sum_{e in rel r -> dst} h[src]) @ W[r]; self-loop = rel 20.
// R9: MLP rebuild of phase 1 (the serial gather was the latency wall).
//  - 512-thread blocks (8 waves), 32 gather groups: waves 0-3 own rl{0,1} of
//    dst g, waves 4-7 own rl{2,3,4} (wave-uniform halves, no divergence).
//    Serial edge chain per group ~halves; 4 blocks/CU * 8 waves = 32 waves/CU
//    (100% of wave cap; LDS ~24.6KB).
//  - batch-4 predicated prefetch in the cell loop: up to 4 hb-row loads in
//    flight per group instead of 1 (the chain was ~700cyc L2/L3 per edge).
//  - spk LDS staging re-added (2KB): src fetch is ds_read_u16, not global.
//  - phase 2 nc-split 8 ways (wave w owns cols [16w,16w+16)), acc = 1x f32x4.

#define NN 50000
#define NE 1600000
#define DIM 128
#define NREL 20
#define NRELP 21
#define TILE 16
#define NTILE (NN / TILE)          // 3125
#define CELLS (NN * 32)            // dst*32 + chunk*8 + rl (rl 0..4 used)
#define SCAN_EPB 2048
#define NBLK_A ((CELLS + SCAN_EPB - 1) / SCAN_EPB)   // 782
#define SPK_CAP 1024               // staged srcs per block (mean 512, sd ~23)
#define PACKED_ELEMS (2 * NRELP * 4 * 8 * 64 * 8)    // 688128

typedef __attribute__((ext_vector_type(8))) short short8;
typedef __attribute__((ext_vector_type(4))) float f32x4;

__device__ __forceinline__ unsigned short f32_to_bf16_raw(float f) {
  union { float f; unsigned u; } c; c.f = f;
  unsigned u = c.u;
  return (unsigned short)((u + 0x7fffu + ((u >> 16) & 1u)) >> 16);  // RNE
}
__device__ __forceinline__ float bf16_raw_to_f32(unsigned short s) {
  union { unsigned u; float f; } c; c.u = ((unsigned)s) << 16;
  return c.f;
}

// ---------------- fp32 -> bf16 (x4), nontemporal stores ----------------
__global__ void cvt_bf16_kernel(const float* __restrict__ in,
                                unsigned short* __restrict__ out, int n4) {
  int i = blockIdx.x * 256 + threadIdx.x;
  if (i < n4) {
    float4 f = ((const float4*)in)[i];
    unsigned long long p =
        (unsigned long long)f32_to_bf16_raw(f.x)
      | ((unsigned long long)f32_to_bf16_raw(f.y) << 16)
      | ((unsigned long long)f32_to_bf16_raw(f.z) << 32)
      | ((unsigned long long)f32_to_bf16_raw(f.w) << 48);
    __builtin_nontemporal_store(p, (unsigned long long*)out + i);  // clean -> L3
  }
}

// ---------------- pack W (+loop_w as rel 20) into B-fragment order ----------------
// WP flat: ((((l*21 + r)*4 + ks)*8 + nc)*64 + lane)*8  (verified R0/R1)
__global__ void pack_w_kernel(const float* __restrict__ W,
                              const float* __restrict__ loop_w,
                              unsigned short* __restrict__ WP) {
  int idx = blockIdx.x * 256 + threadIdx.x;
  if (idx >= PACKED_ELEMS) return;
  int j = idx & 7;       int t = idx >> 3;
  int lane = t & 63;     t >>= 6;
  int nc = t & 7;        t >>= 3;
  int ks = t & 3;        t >>= 2;
  int r = t % NRELP;     int l = t / NRELP;
  int k = ks * 32 + (lane >> 4) * 8 + j;
  int n = nc * 16 + (lane & 15);
  float v = (r < NREL) ? W[(((size_t)l * NREL + r) * DIM + k) * DIM + n]
                       : loop_w[((size_t)l * DIM + k) * DIM + n];
  WP[idx] = f32_to_bf16_raw(v);
}

// ---------------- global cell sort: hist -> scan(A,B,C) -> scatter ----------------
__global__ void hist_kernel(const int* __restrict__ dst, const int* __restrict__ et,
                            unsigned int* __restrict__ cnt, int n) {
  int i = blockIdx.x * 256 + threadIdx.x;
  if (i < n) {
    int e = et[i];
    atomicAdd(&cnt[dst[i] * 32 + (e / 5) * 8 + (e % 5)], 1u);
  }
}

__global__ void scanA_kernel(const unsigned int* __restrict__ cnt,
                             unsigned int* __restrict__ cofs,
                             unsigned int* __restrict__ btot) {
  __shared__ unsigned int buf[256];
  int tid = threadIdx.x;
  int base = blockIdx.x * SCAN_EPB + tid * 8;
  unsigned int v[8], p[8], s = 0;
#pragma unroll
  for (int j = 0; j < 8; ++j) {
    v[j] = (base + j < CELLS) ? cnt[base + j] : 0u;
    p[j] = s; s += v[j];
  }
  buf[tid] = s;
  __syncthreads();
  for (int d = 1; d < 256; d <<= 1) {
    unsigned int a = (tid >= d) ? buf[tid - d] : 0u;
    __syncthreads();
    buf[tid] += a;
    __syncthreads();
  }
  unsigned int excl = buf[tid] - s;
#pragma unroll
  for (int j = 0; j < 8; ++j)
    if (base + j < CELLS) cofs[base + j] = excl + p[j];
  if (tid == 255) btot[blockIdx.x] = buf[255];
}

__global__ void scanB_kernel(unsigned int* __restrict__ btot,
                             unsigned int* __restrict__ cofs) {
  __shared__ unsigned int buf[1024];
  int t = threadIdx.x;
  unsigned int v = (t < NBLK_A) ? btot[t] : 0u;
  buf[t] = v;
  __syncthreads();
  for (int d = 1; d < 1024; d <<= 1) {
    unsigned int a = (t >= d) ? buf[t - d] : 0u;
    __syncthreads();
    buf[t] += a;
    __syncthreads();
  }
  if (t < NBLK_A) btot[t] = buf[t] - v;   // exclusive
  if (t == 1023) cofs[CELLS] = buf[1023]; // = NE sentinel
}

__global__ void scanC_kernel(const unsigned int* __restrict__ btot,
                             unsigned int* __restrict__ cofs,
                             unsigned int* __restrict__ cursor) {
  int base = blockIdx.x * SCAN_EPB + threadIdx.x * 8;
  unsigned int add = btot[blockIdx.x];
#pragma unroll
  for (int j = 0; j < 8; ++j)
    if (base + j < CELLS) {
      unsigned int x = cofs[base + j] + add;
      cofs[base + j] = x;
      cursor[base + j] = x;
    }
}

__global__ void scatter_kernel(const int* __restrict__ src, const int* __restrict__ dst,
                               const int* __restrict__ et,
                               unsigned int* __restrict__ cursor,
                               unsigned short* __restrict__ es, int n) {
  int i = blockIdx.x * 256 + threadIdx.x;
  if (i < n) {
    int e = et[i];
    unsigned int pos = atomicAdd(&cursor[dst[i] * 32 + (e / 5) * 8 + (e % 5)], 1u);
    es[pos] = (unsigned short)src[i];   // N < 65536
  }
}

// ---------------- fused RGCN layer ----------------
// 3125 blocks x 512 threads (8 waves). LDS ~24.6KB -> 4 blocks/CU = 32 waves.
__global__ __launch_bounds__(512, 8) void rgcn_layer_kernel(
    const unsigned short* __restrict__ hb,    // [N,128] bf16
    const unsigned short* __restrict__ WP,    // packed weights
    const float* __restrict__ bias,           // [128] this layer
    int layer,
    const unsigned int* __restrict__ cofs,    // [CELLS+1] cell offsets
    const unsigned short* __restrict__ es,    // [E] srcs, cell-sorted
    float* __restrict__ outf,                 // fp32 out (layer 1) or null
    unsigned short* __restrict__ outb)        // bf16 out (layer 0) or null
{
  // Sb: [16 dst rows][5 rl slots * 16 slot16], slot16 = 8 bf16 (16B),
  // slot index ^= (row & 15) -> conflict-free writes and reads (verified R8).
  __shared__ short8 Sb8[TILE * 80];          // 20480 B
  __shared__ unsigned int cofs_l[513];       // 2052 B
  __shared__ unsigned short spk[SPK_CAP];    // 2048 B

  const int tid  = threadIdx.x;
  const int lane = tid & 63;
  const int w    = tid >> 6;        // wave 0..7
  const int quad = lane >> 4;
  const int m    = lane & 15;
  const int mh8  = (lane & 15) * 8;
  const int half = w >> 2;          // 0: rl{0,1}  1: rl{2,3,4}  (wave-uniform)
  const int g    = (w & 3) * 4 + quad;   // owned dst_local 0..15
  const int dst_base = blockIdx.x * TILE;

  for (int i = tid; i < 513; i += 512) cofs_l[i] = cofs[blockIdx.x * 512 + i];
  __syncthreads();
  const int e0 = (int)cofs_l[0];
  const int etot = (int)cofs_l[512] - e0;
  for (int i = tid; i < etot && i < SPK_CAP; i += 512) spk[i] = es[e0 + i];
  __syncthreads();

  f32x4 acc = (f32x4){0.f, 0.f, 0.f, 0.f};

#define ACC8(hv)                                      \
  do {                                                \
    a0 += bf16_raw_to_f32((unsigned short)(hv)[0]);   \
    a1 += bf16_raw_to_f32((unsigned short)(hv)[1]);   \
    a2 += bf16_raw_to_f32((unsigned short)(hv)[2]);   \
    a3 += bf16_raw_to_f32((unsigned short)(hv)[3]);   \
    a4 += bf16_raw_to_f32((unsigned short)(hv)[4]);   \
    a5 += bf16_raw_to_f32((unsigned short)(hv)[5]);   \
    a6 += bf16_raw_to_f32((unsigned short)(hv)[6]);   \
    a7 += bf16_raw_to_f32((unsigned short)(hv)[7]);   \
  } while (0)

#define GATHER_BODY(SRCI)                                                     \
  for (int i = beg; i < end; i += 4) {                                        \
    const int n = end - i;                                                    \
    short8 h0, h1, h2, h3;                                                    \
    h0 = *(const short8*)(hb + (size_t)(SRCI(i)) * DIM + mh8);                \
    if (n > 1) h1 = *(const short8*)(hb + (size_t)(SRCI(i + 1)) * DIM + mh8); \
    if (n > 2) h2 = *(const short8*)(hb + (size_t)(SRCI(i + 2)) * DIM + mh8); \
    if (n > 3) h3 = *(const short8*)(hb + (size_t)(SRCI(i + 3)) * DIM + mh8); \
    ACC8(h0);                                                                 \
    if (n > 1) ACC8(h1);                                                      \
    if (n > 2) ACC8(h2);                                                      \
    if (n > 3) ACC8(h3);                                                      \
  }

#define SRC_LDS(i) (int)spk[(i)]
#define SRC_GBL(i) (int)es[e0 + (i)]

  auto do_cell = [&](int c, int rl) {
    const int idx = g * 32 + c * 8 + rl;
    const int beg = (int)cofs_l[idx] - e0;
    const int end = (int)cofs_l[idx + 1] - e0;
    float a0 = 0.f, a1 = 0.f, a2 = 0.f, a3 = 0.f;
    float a4 = 0.f, a5 = 0.f, a6 = 0.f, a7 = 0.f;
    if (end <= SPK_CAP) {
      GATHER_BODY(SRC_LDS)
    } else {            // overflow fallback (essentially never taken)
      GATHER_BODY(SRC_GBL)
    }
    short8 p;
    p[0] = (short)f32_to_bf16_raw(a0);
    p[1] = (short)f32_to_bf16_raw(a1);
    p[2] = (short)f32_to_bf16_raw(a2);
    p[3] = (short)f32_to_bf16_raw(a3);
    p[4] = (short)f32_to_bf16_raw(a4);
    p[5] = (short)f32_to_bf16_raw(a5);
    p[6] = (short)f32_to_bf16_raw(a6);
    p[7] = (short)f32_to_bf16_raw(a7);
    Sb8[g * 80 + ((rl * 16 + m) ^ g)] = p;
  };

  for (int c = 0; c < 5; ++c) {
    // ---- phase 1: wave-uniform rel-split gather ----
    if (c < 4) {
      if (half == 0) {
        do_cell(c, 0);
        do_cell(c, 1);
      } else {
        do_cell(c, 2);
        do_cell(c, 3);
        do_cell(c, 4);
      }
    } else if (half == 0) {
      // self-loop mini-chunk: own row (feeds rel 20 = loop_w), slot 0
      short8 hv = *(const short8*)(hb + (size_t)(dst_base + g) * DIM + mh8);
      Sb8[g * 80 + (m ^ g)] = hv;   // already bf16; sum of one row
    }
    __syncthreads();

    // ---- phase 2: nc-split 8 ways. wave w owns cols [16w,16w+16) ----
    const int rc = (c == 4) ? 1 : 5;
    for (int rl = 0; rl < rc; ++rl) {
      const int r = (c == 4) ? (NRELP - 1) : (c * 5 + rl);
      const unsigned short* bp =
          WP + ((((size_t)(layer * NRELP + r) * 4) * 8 + w) * 64 + lane) * 8;
#pragma unroll
      for (int ks = 0; ks < 4; ++ks) {
        short8 a = Sb8[m * 80 + ((rl * 16 + ks * 4 + quad) ^ m)];
        short8 b = *(const short8*)(bp + (size_t)ks * 4096);
        acc = __builtin_amdgcn_mfma_f32_16x16x32_bf16(a, b, acc, 0, 0, 0);
      }
    }
    __syncthreads();
  }

  // ---- epilogue: wave w stores its 16-col tile; no cross-wave reduction ----
  const int col = w * 16 + m;
  const float bv = bias[col];
  if (outb) {
#pragma unroll
    for (int i = 0; i < 4; ++i)
      outb[(size_t)(dst_base + quad * 4 + i) * DIM + col] =
          f32_to_bf16_raw(acc[i] + bv);
  } else {
#pragma unroll
    for (int i = 0; i < 4; ++i)
      outf[(size_t)(dst_base + quad * 4 + i) * DIM + col] = acc[i] + bv;
  }
#undef ACC8
#undef GATHER_BODY
#undef SRC_LDS
#undef SRC_GBL
}

// ---------------- launch ----------------
extern "C" void kernel_launch(void* const* d_in, const int* in_sizes, int n_in,
                              void* d_out, int out_size, void* d_ws, size_t ws_size,
                              hipStream_t stream) {
  const float* h0     = (const float*)d_in[0];
  const float* W      = (const float*)d_in[1];
  const float* loop_w = (const float*)d_in[2];
  const float* bias   = (const float*)d_in[3];
  const int* esrc     = (const int*)d_in[4];
  const int* edst     = (const int*)d_in[5];
  const int* etyp     = (const int*)d_in[6];
  float* out = (float*)d_out;

  char* ws = (char*)d_ws;
  size_t off = 0;
  auto alloc = [&](size_t bytes) -> void* {
    void* p = ws + off;
    off = (off + bytes + 255) & ~(size_t)255;
    return p;
  };
  unsigned short* hb0   = (unsigned short*)alloc((size_t)NN * DIM * 2);   // 12.8 MB
  unsigned short* hb1   = (unsigned short*)alloc((size_t)NN * DIM * 2);   // 12.8 MB
  unsigned short* WP    = (unsigned short*)alloc((size_t)PACKED_ELEMS * 2);
  unsigned int*   cnt   = (unsigned int*)alloc((size_t)CELLS * 4);        // 6.4 MB
  unsigned int*   cofs  = (unsigned int*)alloc((size_t)(CELLS + 1) * 4);  // 6.4 MB
  unsigned int*   cursor= (unsigned int*)alloc((size_t)CELLS * 4);        // 6.4 MB
  unsigned int*   btot  = (unsigned int*)alloc((size_t)NBLK_A * 4);
  unsigned short* es    = (unsigned short*)alloc((size_t)NE * 2);         // 3.2 MB

  (void)hipMemsetAsync(cnt, 0, (size_t)CELLS * 4, stream);
  hist_kernel<<<NE / 256, 256, 0, stream>>>(edst, etyp, cnt, NE);
  scanA_kernel<<<NBLK_A, 256, 0, stream>>>(cnt, cofs, btot);
  scanB_kernel<<<1, 1024, 0, stream>>>(btot, cofs);
  scanC_kernel<<<NBLK_A, 256, 0, stream>>>(btot, cofs, cursor);
  scatter_kernel<<<NE / 256, 256, 0, stream>>>(esrc, edst, etyp, cursor, es, NE);

  pack_w_kernel<<<(PACKED_ELEMS + 255) / 256, 256, 0, stream>>>(W, loop_w, WP);
  cvt_bf16_kernel<<<(NN * DIM / 4 + 255) / 256, 256, 0, stream>>>(h0, hb0, NN * DIM / 4);

  rgcn_layer_kernel<<<NTILE, 512, 0, stream>>>(hb0, WP, bias, 0, cofs, es,
                                               nullptr, hb1);
  rgcn_layer_kernel<<<NTILE, 512, 0, stream>>>(hb1, WP, bias + DIM, 1, cofs, es,
                                               out, nullptr);
}

// Round 3
// 528.075 us; speedup vs baseline: 1.4012x; 1.0057x over previous
//
#include <hip/hip_runtime.h>
#include <hip/hip_bf16.h>
#include <stdint.h>

// GNN_758: stacked RelGraphConv x2.  N=50000, E=1.6M, D=128, R=20.
// agg[dst] = sum_r (sum_{e in rel r -> dst} h[src]) @ W[r]; self-loop = rel 20.
// R10: (a) merged-range gather walk: each 16-lane group walks its contiguous
//      rl-subset range once (boundary-flush demux via cofs_l) instead of one
//      loop per tiny cell -> divergence inflation ~2.5x -> ~1.5x, per-cell
//      setup gone, batch-4 loads stay in flight across cell boundaries.
//      (b) CELLS 1.6M -> 1M: sort key dst*20+r (8-slot padding dropped);
//      37.5% less memset/hist/scan/scatter traffic, cofs_l 513 -> 321 words.

#define NN 50000
#define NE 1600000
#define DIM 128
#define NREL 20
#define NRELP 21
#define TILE 16
#define NTILE (NN / TILE)          // 3125
#define CELLS (NN * NREL)          // dst*20 + r  (r = chunk*5 + rl)
#define SCAN_EPB 2048
#define NBLK_A ((CELLS + SCAN_EPB - 1) / SCAN_EPB)   // 489
#define SPK_CAP 1024               // staged srcs per block (mean 512, sd ~23)
#define PACKED_ELEMS (2 * NRELP * 4 * 8 * 64 * 8)    // 688128

typedef __attribute__((ext_vector_type(8))) short short8;
typedef __attribute__((ext_vector_type(4))) float f32x4;

__device__ __forceinline__ unsigned short f32_to_bf16_raw(float f) {
  union { float f; unsigned u; } c; c.f = f;
  unsigned u = c.u;
  return (unsigned short)((u + 0x7fffu + ((u >> 16) & 1u)) >> 16);  // RNE
}
__device__ __forceinline__ float bf16_raw_to_f32(unsigned short s) {
  union { unsigned u; float f; } c; c.u = ((unsigned)s) << 16;
  return c.f;
}

// ---------------- fp32 -> bf16 (x4), nontemporal stores ----------------
__global__ void cvt_bf16_kernel(const float* __restrict__ in,
                                unsigned short* __restrict__ out, int n4) {
  int i = blockIdx.x * 256 + threadIdx.x;
  if (i < n4) {
    float4 f = ((const float4*)in)[i];
    unsigned long long p =
        (unsigned long long)f32_to_bf16_raw(f.x)
      | ((unsigned long long)f32_to_bf16_raw(f.y) << 16)
      | ((unsigned long long)f32_to_bf16_raw(f.z) << 32)
      | ((unsigned long long)f32_to_bf16_raw(f.w) << 48);
    __builtin_nontemporal_store(p, (unsigned long long*)out + i);  // clean -> L3
  }
}

// ---------------- pack W (+loop_w as rel 20) into B-fragment order ----------------
// WP flat: ((((l*21 + r)*4 + ks)*8 + nc)*64 + lane)*8  (verified R0/R1)
__global__ void pack_w_kernel(const float* __restrict__ W,
                              const float* __restrict__ loop_w,
                              unsigned short* __restrict__ WP) {
  int idx = blockIdx.x * 256 + threadIdx.x;
  if (idx >= PACKED_ELEMS) return;
  int j = idx & 7;       int t = idx >> 3;
  int lane = t & 63;     t >>= 6;
  int nc = t & 7;        t >>= 3;
  int ks = t & 3;        t >>= 2;
  int r = t % NRELP;     int l = t / NRELP;
  int k = ks * 32 + (lane >> 4) * 8 + j;
  int n = nc * 16 + (lane & 15);
  float v = (r < NREL) ? W[(((size_t)l * NREL + r) * DIM + k) * DIM + n]
                       : loop_w[((size_t)l * DIM + k) * DIM + n];
  WP[idx] = f32_to_bf16_raw(v);
}

// ---------------- global cell sort: hist -> scan(A,B,C) -> scatter ----------------
__global__ void hist_kernel(const int* __restrict__ dst, const int* __restrict__ et,
                            unsigned int* __restrict__ cnt, int n) {
  int i = blockIdx.x * 256 + threadIdx.x;
  if (i < n) atomicAdd(&cnt[dst[i] * NREL + et[i]], 1u);
}

__global__ void scanA_kernel(const unsigned int* __restrict__ cnt,
                             unsigned int* __restrict__ cofs,
                             unsigned int* __restrict__ btot) {
  __shared__ unsigned int buf[256];
  int tid = threadIdx.x;
  int base = blockIdx.x * SCAN_EPB + tid * 8;
  unsigned int v[8], p[8], s = 0;
#pragma unroll
  for (int j = 0; j < 8; ++j) {
    v[j] = (base + j < CELLS) ? cnt[base + j] : 0u;
    p[j] = s; s += v[j];
  }
  buf[tid] = s;
  __syncthreads();
  for (int d = 1; d < 256; d <<= 1) {
    unsigned int a = (tid >= d) ? buf[tid - d] : 0u;
    __syncthreads();
    buf[tid] += a;
    __syncthreads();
  }
  unsigned int excl = buf[tid] - s;
#pragma unroll
  for (int j = 0; j < 8; ++j)
    if (base + j < CELLS) cofs[base + j] = excl + p[j];
  if (tid == 255) btot[blockIdx.x] = buf[255];
}

__global__ void scanB_kernel(unsigned int* __restrict__ btot,
                             unsigned int* __restrict__ cofs) {
  __shared__ unsigned int buf[1024];
  int t = threadIdx.x;
  unsigned int v = (t < NBLK_A) ? btot[t] : 0u;
  buf[t] = v;
  __syncthreads();
  for (int d = 1; d < 1024; d <<= 1) {
    unsigned int a = (t >= d) ? buf[t - d] : 0u;
    __syncthreads();
    buf[t] += a;
    __syncthreads();
  }
  if (t < NBLK_A) btot[t] = buf[t] - v;   // exclusive
  if (t == 1023) cofs[CELLS] = buf[1023]; // = NE sentinel
}

__global__ void scanC_kernel(const unsigned int* __restrict__ btot,
                             unsigned int* __restrict__ cofs,
                             unsigned int* __restrict__ cursor) {
  int base = blockIdx.x * SCAN_EPB + threadIdx.x * 8;
  unsigned int add = btot[blockIdx.x];
#pragma unroll
  for (int j = 0; j < 8; ++j)
    if (base + j < CELLS) {
      unsigned int x = cofs[base + j] + add;
      cofs[base + j] = x;
      cursor[base + j] = x;
    }
}

__global__ void scatter_kernel(const int* __restrict__ src, const int* __restrict__ dst,
                               const int* __restrict__ et,
                               unsigned int* __restrict__ cursor,
                               unsigned short* __restrict__ es, int n) {
  int i = blockIdx.x * 256 + threadIdx.x;
  if (i < n) {
    unsigned int pos = atomicAdd(&cursor[dst[i] * NREL + et[i]], 1u);
    es[pos] = (unsigned short)src[i];   // N < 65536
  }
}

// ---------------- fused RGCN layer ----------------
// 3125 blocks x 512 threads (8 waves). LDS ~23.3KB -> 4 blocks/CU = 32 waves.
__global__ __launch_bounds__(512, 8) void rgcn_layer_kernel(
    const unsigned short* __restrict__ hb,    // [N,128] bf16
    const unsigned short* __restrict__ WP,    // packed weights
    const float* __restrict__ bias,           // [128] this layer
    int layer,
    const unsigned int* __restrict__ cofs,    // [CELLS+1] cell offsets
    const unsigned short* __restrict__ es,    // [E] srcs, cell-sorted
    float* __restrict__ outf,                 // fp32 out (layer 1) or null
    unsigned short* __restrict__ outb)        // bf16 out (layer 0) or null
{
  // Sb: [16 dst rows][5 rl slots * 16 slot16], slot16 = 8 bf16 (16B),
  // slot index ^= (row & 15) -> conflict-free writes and reads (verified R8).
  __shared__ short8 Sb8[TILE * 80];          // 20480 B
  __shared__ unsigned int cofs_l[321];       // 1284 B
  __shared__ unsigned short spk[SPK_CAP];    // 2048 B

  const int tid  = threadIdx.x;
  const int lane = tid & 63;
  const int w    = tid >> 6;        // wave 0..7
  const int quad = lane >> 4;
  const int m    = lane & 15;
  const int mh8  = m * 8;
  const int half = w >> 2;          // 0: rl{0,1}  1: rl{2,3,4}  (wave-uniform)
  const int g    = (w & 3) * 4 + quad;   // owned dst_local 0..15
  const int dst_base = blockIdx.x * TILE;

  for (int i = tid; i < 321; i += 512) cofs_l[i] = cofs[blockIdx.x * (TILE * NREL) + i];
  __syncthreads();
  const int e0 = (int)cofs_l[0];
  const int etot = (int)cofs_l[320] - e0;
  for (int i = tid; i < etot && i < SPK_CAP; i += 512) spk[i] = es[e0 + i];
  __syncthreads();

  f32x4 acc = (f32x4){0.f, 0.f, 0.f, 0.f};

  for (int c = 0; c < 5; ++c) {
    // ---- phase 1: merged-range walk with boundary-flush rl demux ----
    if (c < 4) {
      const int cbase = g * NREL + c * 5;
      const int rlA = half ? 2 : 0;
      const int rlB = half ? 5 : 2;
      const int beg    = (int)cofs_l[cbase + rlA] - e0;
      const int endAll = (int)cofs_l[cbase + rlB] - e0;

      float a0 = 0.f, a1 = 0.f, a2 = 0.f, a3 = 0.f;
      float a4 = 0.f, a5 = 0.f, a6 = 0.f, a7 = 0.f;
      int rl = rlA;
      int nend = (int)cofs_l[cbase + rl + 1] - e0;

      auto flush = [&]() {
        short8 p;
        p[0] = (short)f32_to_bf16_raw(a0);
        p[1] = (short)f32_to_bf16_raw(a1);
        p[2] = (short)f32_to_bf16_raw(a2);
        p[3] = (short)f32_to_bf16_raw(a3);
        p[4] = (short)f32_to_bf16_raw(a4);
        p[5] = (short)f32_to_bf16_raw(a5);
        p[6] = (short)f32_to_bf16_raw(a6);
        p[7] = (short)f32_to_bf16_raw(a7);
        Sb8[g * 80 + ((rl * 16 + m) ^ g)] = p;
        a0 = a1 = a2 = a3 = a4 = a5 = a6 = a7 = 0.f;
      };
      auto bump = [&](int i) {    // advance cell state past edge index i
        while (i >= nend) {
          flush();
          ++rl;
          nend = (int)cofs_l[cbase + rl + 1] - e0;
        }
      };
      auto add8 = [&](short8 hv) {
        a0 += bf16_raw_to_f32((unsigned short)hv[0]);
        a1 += bf16_raw_to_f32((unsigned short)hv[1]);
        a2 += bf16_raw_to_f32((unsigned short)hv[2]);
        a3 += bf16_raw_to_f32((unsigned short)hv[3]);
        a4 += bf16_raw_to_f32((unsigned short)hv[4]);
        a5 += bf16_raw_to_f32((unsigned short)hv[5]);
        a6 += bf16_raw_to_f32((unsigned short)hv[6]);
        a7 += bf16_raw_to_f32((unsigned short)hv[7]);
      };
      auto run_walk = [&](auto fetch) {
        for (int i = beg; i < endAll; i += 4) {
          const int nrem = endAll - i;
          short8 h0, h1, h2, h3;
          h0 = fetch(i);
          if (nrem > 1) h1 = fetch(i + 1);
          if (nrem > 2) h2 = fetch(i + 2);
          if (nrem > 3) h3 = fetch(i + 3);
          bump(i);      add8(h0);
          if (nrem > 1) { bump(i + 1); add8(h1); }
          if (nrem > 2) { bump(i + 2); add8(h2); }
          if (nrem > 3) { bump(i + 3); add8(h3); }
        }
        while (rl < rlB) { flush(); ++rl; }   // trailing (incl. empty) cells
      };

      if (endAll <= SPK_CAP) {
        run_walk([&](int i) {
          return *(const short8*)(hb + (size_t)spk[i] * DIM + mh8);
        });
      } else {   // overflow fallback (essentially never taken)
        run_walk([&](int i) {
          return *(const short8*)(hb + (size_t)es[e0 + i] * DIM + mh8);
        });
      }
    } else if (half == 0) {
      // self-loop mini-chunk: own row (feeds rel 20 = loop_w), slot 0
      short8 hv = *(const short8*)(hb + (size_t)(dst_base + g) * DIM + mh8);
      Sb8[g * 80 + (m ^ g)] = hv;   // already bf16; sum of one row
    }
    __syncthreads();

    // ---- phase 2: nc-split 8 ways. wave w owns cols [16w,16w+16) ----
    const int rc = (c == 4) ? 1 : 5;
    for (int rl2 = 0; rl2 < rc; ++rl2) {
      const int r = (c == 4) ? (NRELP - 1) : (c * 5 + rl2);
      const unsigned short* bp =
          WP + ((((size_t)(layer * NRELP + r) * 4) * 8 + w) * 64 + lane) * 8;
#pragma unroll
      for (int ks = 0; ks < 4; ++ks) {
        short8 a = Sb8[m * 80 + ((rl2 * 16 + ks * 4 + quad) ^ m)];
        short8 b = *(const short8*)(bp + (size_t)ks * 4096);
        acc = __builtin_amdgcn_mfma_f32_16x16x32_bf16(a, b, acc, 0, 0, 0);
      }
    }
    __syncthreads();
  }

  // ---- epilogue: wave w stores its 16-col tile; no cross-wave reduction ----
  const int col = w * 16 + m;
  const float bv = bias[col];
  if (outb) {
#pragma unroll
    for (int i = 0; i < 4; ++i)
      outb[(size_t)(dst_base + quad * 4 + i) * DIM + col] =
          f32_to_bf16_raw(acc[i] + bv);
  } else {
#pragma unroll
    for (int i = 0; i < 4; ++i)
      outf[(size_t)(dst_base + quad * 4 + i) * DIM + col] = acc[i] + bv;
  }
}

// ---------------- launch ----------------
extern "C" void kernel_launch(void* const* d_in, const int* in_sizes, int n_in,
                              void* d_out, int out_size, void* d_ws, size_t ws_size,
                              hipStream_t stream) {
  const float* h0     = (const float*)d_in[0];
  const float* W      = (const float*)d_in[1];
  const float* loop_w = (const float*)d_in[2];
  const float* bias   = (const float*)d_in[3];
  const int* esrc     = (const int*)d_in[4];
  const int* edst     = (const int*)d_in[5];
  const int* etyp     = (const int*)d_in[6];
  float* out = (float*)d_out;

  char* ws = (char*)d_ws;
  size_t off = 0;
  auto alloc = [&](size_t bytes) -> void* {
    void* p = ws + off;
    off = (off + bytes + 255) & ~(size_t)255;
    return p;
  };
  unsigned short* hb0   = (unsigned short*)alloc((size_t)NN * DIM * 2);   // 12.8 MB
  unsigned short* hb1   = (unsigned short*)alloc((size_t)NN * DIM * 2);   // 12.8 MB
  unsigned short* WP    = (unsigned short*)alloc((size_t)PACKED_ELEMS * 2);
  unsigned int*   cnt   = (unsigned int*)alloc((size_t)CELLS * 4);        // 4 MB
  unsigned int*   cofs  = (unsigned int*)alloc((size_t)(CELLS + 1) * 4);  // 4 MB
  unsigned int*   cursor= (unsigned int*)alloc((size_t)CELLS * 4);        // 4 MB
  unsigned int*   btot  = (unsigned int*)alloc((size_t)NBLK_A * 4);
  unsigned short* es    = (unsigned short*)alloc((size_t)NE * 2);         // 3.2 MB

  (void)hipMemsetAsync(cnt, 0, (size_t)CELLS * 4, stream);
  hist_kernel<<<NE / 256, 256, 0, stream>>>(edst, etyp, cnt, NE);
  scanA_kernel<<<NBLK_A, 256, 0, stream>>>(cnt, cofs, btot);
  scanB_kernel<<<1, 1024, 0, stream>>>(btot, cofs);
  scanC_kernel<<<NBLK_A, 256, 0, stream>>>(btot, cofs, cursor);
  scatter_kernel<<<NE / 256, 256, 0, stream>>>(esrc, edst, etyp, cursor, es, NE);

  pack_w_kernel<<<(PACKED_ELEMS + 255) / 256, 256, 0, stream>>>(W, loop_w, WP);
  cvt_bf16_kernel<<<(NN * DIM / 4 + 255) / 256, 256, 0, stream>>>(h0, hb0, NN * DIM / 4);

  rgcn_layer_kernel<<<NTILE, 512, 0, stream>>>(hb0, WP, bias, 0, cofs, es,
                                               nullptr, hb1);
  rgcn_layer_kernel<<<NTILE, 512, 0, stream>>>(hb1, WP, bias + DIM, 1, cofs, es,
                                               out, nullptr);
}

// Round 4
// 404.814 us; speedup vs baseline: 1.8279x; 1.3045x over previous
//
#include <hip/hip_runtime.h>
#include <hip/hip_bf16.h>
#include <stdint.h>

// GNN_758: stacked RelGraphConv x2.  N=50000, E=1.6M, D=128, R=20.
// agg[dst] = sum_r (sum_{e in rel r -> dst} h[src]) @ W[r]; self-loop = rel 20.
// R11: (a) preprocessing rebuilt as two-level LDS-privatized counting sort:
//      tile_count (LDS hist over 3125 tiles) -> scan -> tile_scatter (LDS
//      cursors, u32 payload src|dstLow|rel) -> tile_sort (per-tile 320-bin
//      LDS hist+scan, writes cofs + cell-sorted es). ZERO device-scope
//      atomics (was 3.2M random ones in hist+scatter = the ~260us wall).
//      (b) layer kernel: flush via v_cvt_pk_bf16_f32 (1 instr/2 elems vs
//      ~5/elem manual RNE); unpack via dword ops (u<<16, u&0xffff0000).

#define NN 50000
#define NE 1600000
#define DIM 128
#define NREL 20
#define NRELP 21
#define TILE 16
#define NTILE (NN / TILE)          // 3125
#define CELLS (NN * NREL)          // dst*20 + r
#define CHB 200                    // chunk blocks for count/scatter
#define CHE (NE / CHB)             // 8000 edges per chunk block
#define TT_N (NTILE * CHB)         // 625000 (tile,blk) table
#define SCAN_EPB 2048
#define NBLK_TT ((TT_N + SCAN_EPB - 1) / SCAN_EPB)   // 306
#define SPK_CAP 1024               // staged srcs per block (mean 512, sd ~23)
#define PACKED_ELEMS (2 * NRELP * 4 * 8 * 64 * 8)    // 688128

typedef __attribute__((ext_vector_type(8))) short short8;
typedef __attribute__((ext_vector_type(4))) float f32x4;

__device__ __forceinline__ unsigned short f32_to_bf16_raw(float f) {
  union { float f; unsigned u; } c; c.f = f;
  unsigned u = c.u;
  return (unsigned short)((u + 0x7fffu + ((u >> 16) & 1u)) >> 16);  // RNE
}
__device__ __forceinline__ unsigned cvt_pk_bf16(float lo, float hi) {
  unsigned r;   // bits 0-15 = bf16(lo), 16-31 = bf16(hi), RNE (gfx950)
  asm("v_cvt_pk_bf16_f32 %0, %1, %2" : "=v"(r) : "v"(lo), "v"(hi));
  return r;
}

// ---------------- fp32 -> bf16 (x4), nontemporal stores ----------------
__global__ void cvt_bf16_kernel(const float* __restrict__ in,
                                unsigned short* __restrict__ out, int n4) {
  int i = blockIdx.x * 256 + threadIdx.x;
  if (i < n4) {
    float4 f = ((const float4*)in)[i];
    unsigned long long p =
        (unsigned long long)cvt_pk_bf16(f.x, f.y)
      | ((unsigned long long)cvt_pk_bf16(f.z, f.w) << 32);
    __builtin_nontemporal_store(p, (unsigned long long*)out + i);  // clean -> L3
  }
}

// ---------------- pack W (+loop_w as rel 20) into B-fragment order ----------------
// WP flat: ((((l*21 + r)*4 + ks)*8 + nc)*64 + lane)*8  (verified R0/R1)
__global__ void pack_w_kernel(const float* __restrict__ W,
                              const float* __restrict__ loop_w,
                              unsigned short* __restrict__ WP) {
  int idx = blockIdx.x * 256 + threadIdx.x;
  if (idx >= PACKED_ELEMS) return;
  int j = idx & 7;       int t = idx >> 3;
  int lane = t & 63;     t >>= 6;
  int nc = t & 7;        t >>= 3;
  int ks = t & 3;        t >>= 2;
  int r = t % NRELP;     int l = t / NRELP;
  int k = ks * 32 + (lane >> 4) * 8 + j;
  int n = nc * 16 + (lane & 15);
  float v = (r < NREL) ? W[(((size_t)l * NREL + r) * DIM + k) * DIM + n]
                       : loop_w[((size_t)l * DIM + k) * DIM + n];
  WP[idx] = f32_to_bf16_raw(v);
}

// ---------------- two-level counting sort (no device atomics) ----------------
// Level 1: bucket by tile (dst>>4), 3125 bins, LDS-privatized per chunk block.
__global__ __launch_bounds__(256) void tile_count_kernel(
    const int* __restrict__ dst, unsigned int* __restrict__ tt) {
  __shared__ unsigned int hist[NTILE];           // 12.5 KB
  for (int i = threadIdx.x; i < NTILE; i += 256) hist[i] = 0u;
  __syncthreads();
  const int base = blockIdx.x * CHE;
  for (int i = base + threadIdx.x; i < base + CHE; i += 256)
    atomicAdd(&hist[dst[i] >> 4], 1u);           // LDS atomic
  __syncthreads();
  for (int i = threadIdx.x; i < NTILE; i += 256)
    tt[(size_t)i * CHB + blockIdx.x] = hist[i];  // (bin, blk) layout for scan
}

__global__ void scanA_kernel(const unsigned int* __restrict__ in,
                             unsigned int* __restrict__ out,
                             unsigned int* __restrict__ btot, int n) {
  __shared__ unsigned int buf[256];
  int tid = threadIdx.x;
  int base = blockIdx.x * SCAN_EPB + tid * 8;
  unsigned int v[8], p[8], s = 0;
#pragma unroll
  for (int j = 0; j < 8; ++j) {
    v[j] = (base + j < n) ? in[base + j] : 0u;
    p[j] = s; s += v[j];
  }
  buf[tid] = s;
  __syncthreads();
  for (int d = 1; d < 256; d <<= 1) {
    unsigned int a = (tid >= d) ? buf[tid - d] : 0u;
    __syncthreads();
    buf[tid] += a;
    __syncthreads();
  }
  unsigned int excl = buf[tid] - s;
#pragma unroll
  for (int j = 0; j < 8; ++j)
    if (base + j < n) out[base + j] = excl + p[j];
  if (tid == 255) btot[blockIdx.x] = buf[255];
}

__global__ void scanB_kernel(unsigned int* __restrict__ btot,
                             unsigned int* __restrict__ out, int nblk, int n) {
  __shared__ unsigned int buf[1024];
  int t = threadIdx.x;
  unsigned int v = (t < nblk) ? btot[t] : 0u;
  buf[t] = v;
  __syncthreads();
  for (int d = 1; d < 1024; d <<= 1) {
    unsigned int a = (t >= d) ? buf[t - d] : 0u;
    __syncthreads();
    buf[t] += a;
    __syncthreads();
  }
  if (t < nblk) btot[t] = buf[t] - v;   // exclusive
  if (t == 1023) out[n] = buf[1023];    // sentinel = NE
}

__global__ void scanC_kernel(const unsigned int* __restrict__ btot,
                             unsigned int* __restrict__ out, int n) {
  int base = blockIdx.x * SCAN_EPB + threadIdx.x * 8;
  unsigned int add = btot[blockIdx.x];
#pragma unroll
  for (int j = 0; j < 8; ++j)
    if (base + j < n) out[base + j] += add;
}

// Level-1 scatter: payload u32 = src | dstLow4<<16 | rel<<20, tile-bucketed.
__global__ __launch_bounds__(256) void tile_scatter_kernel(
    const int* __restrict__ src, const int* __restrict__ dst,
    const int* __restrict__ et, const unsigned int* __restrict__ tts,
    unsigned int* __restrict__ ep) {
  __shared__ unsigned int cur[NTILE];            // 12.5 KB
  for (int i = threadIdx.x; i < NTILE; i += 256)
    cur[i] = tts[(size_t)i * CHB + blockIdx.x];
  __syncthreads();
  const int base = blockIdx.x * CHE;
  for (int i = base + threadIdx.x; i < base + CHE; i += 256) {
    int d = dst[i];
    unsigned int pos = atomicAdd(&cur[d >> 4], 1u);   // LDS atomic
    ep[pos] = (unsigned int)src[i] | ((unsigned int)(d & 15) << 16)
            | ((unsigned int)et[i] << 20);
  }
}

// Level 2: per-tile 320-bin sort -> cofs (dst*20+r layout) + es (u16 src).
__global__ __launch_bounds__(512) void tile_sort_kernel(
    const unsigned int* __restrict__ ep, const unsigned int* __restrict__ tts,
    unsigned short* __restrict__ es, unsigned int* __restrict__ cofs) {
  __shared__ unsigned int hist[512];             // 320 bins, padded for scan
  const int t = threadIdx.x;
  const int tile = blockIdx.x;
  const unsigned int start = tts[(size_t)tile * CHB];
  const unsigned int end = (tile + 1 < NTILE) ? tts[(size_t)(tile + 1) * CHB]
                                              : (unsigned int)NE;
  const int cnt = (int)(end - start);
  hist[t] = 0u;
  __syncthreads();
  for (int i = t; i < cnt; i += 512) {
    unsigned int p = ep[start + i];
    atomicAdd(&hist[((p >> 16) & 15u) * 20u + (p >> 20)], 1u);
  }
  __syncthreads();
  unsigned int own = hist[t];
  for (int d = 1; d < 512; d <<= 1) {
    __syncthreads();
    unsigned int a = (t >= d) ? hist[t - d] : 0u;
    __syncthreads();
    hist[t] += a;
  }
  __syncthreads();
  unsigned int excl = hist[t] - own;     // exclusive prefix (own slot only)
  hist[t] = excl;                        // becomes rank cursor
  if (t < 320) cofs[(size_t)tile * 320 + t] = start + excl;
  if (tile == NTILE - 1 && t == 0) cofs[CELLS] = (unsigned int)NE;
  __syncthreads();
  for (int i = t; i < cnt; i += 512) {
    unsigned int p = ep[start + i];
    int sub = (int)(((p >> 16) & 15u) * 20u + (p >> 20));
    unsigned int rk = atomicAdd(&hist[sub], 1u);
    es[start + rk] = (unsigned short)(p & 0xffffu);
  }
}

// ---------------- fused RGCN layer ----------------
// 3125 blocks x 512 threads (8 waves). LDS ~23.3KB -> 4 blocks/CU = 32 waves.
__global__ __launch_bounds__(512, 8) void rgcn_layer_kernel(
    const unsigned short* __restrict__ hb,    // [N,128] bf16
    const unsigned short* __restrict__ WP,    // packed weights
    const float* __restrict__ bias,           // [128] this layer
    int layer,
    const unsigned int* __restrict__ cofs,    // [CELLS+1] cell offsets
    const unsigned short* __restrict__ es,    // [E] srcs, cell-sorted
    float* __restrict__ outf,                 // fp32 out (layer 1) or null
    unsigned short* __restrict__ outb)        // bf16 out (layer 0) or null
{
  // Sb: [16 dst rows][5 rl slots * 16 slot16], slot16 = 8 bf16 (16B),
  // slot index ^= (row & 15) -> conflict-free writes and reads (verified R8).
  __shared__ short8 Sb8[TILE * 80];          // 20480 B
  __shared__ unsigned int cofs_l[321];       // 1284 B
  __shared__ unsigned short spk[SPK_CAP];    // 2048 B

  const int tid  = threadIdx.x;
  const int lane = tid & 63;
  const int w    = tid >> 6;        // wave 0..7
  const int quad = lane >> 4;
  const int m    = lane & 15;
  const int mh8  = m * 8;
  const int half = w >> 2;          // 0: rl{0,1}  1: rl{2,3,4}  (wave-uniform)
  const int g    = (w & 3) * 4 + quad;   // owned dst_local 0..15
  const int dst_base = blockIdx.x * TILE;

  for (int i = tid; i < 321; i += 512) cofs_l[i] = cofs[blockIdx.x * (TILE * NREL) + i];
  __syncthreads();
  const int e0 = (int)cofs_l[0];
  const int etot = (int)cofs_l[320] - e0;
  for (int i = tid; i < etot && i < SPK_CAP; i += 512) spk[i] = es[e0 + i];
  __syncthreads();

  f32x4 acc = (f32x4){0.f, 0.f, 0.f, 0.f};

  for (int c = 0; c < 5; ++c) {
    // ---- phase 1: merged-range walk with boundary-flush rl demux ----
    if (c < 4) {
      const int cbase = g * NREL + c * 5;
      const int rlA = half ? 2 : 0;
      const int rlB = half ? 5 : 2;
      const int beg    = (int)cofs_l[cbase + rlA] - e0;
      const int endAll = (int)cofs_l[cbase + rlB] - e0;

      float a0 = 0.f, a1 = 0.f, a2 = 0.f, a3 = 0.f;
      float a4 = 0.f, a5 = 0.f, a6 = 0.f, a7 = 0.f;
      int rl = rlA;
      int nend = (int)cofs_l[cbase + rl + 1] - e0;

      auto flush = [&]() {
        union { uint4 u; short8 s; } pk;
        pk.u.x = cvt_pk_bf16(a0, a1);
        pk.u.y = cvt_pk_bf16(a2, a3);
        pk.u.z = cvt_pk_bf16(a4, a5);
        pk.u.w = cvt_pk_bf16(a6, a7);
        Sb8[g * 80 + ((rl * 16 + m) ^ g)] = pk.s;
        a0 = a1 = a2 = a3 = a4 = a5 = a6 = a7 = 0.f;
      };
      auto bump = [&](int i) {    // advance cell state past edge index i
        while (i >= nend) {
          flush();
          ++rl;
          nend = (int)cofs_l[cbase + rl + 1] - e0;
        }
      };
      auto add8 = [&](short8 hv) {
        union { short8 s; uint4 u; } cv; cv.s = hv;
        a0 += __uint_as_float(cv.u.x << 16);
        a1 += __uint_as_float(cv.u.x & 0xffff0000u);
        a2 += __uint_as_float(cv.u.y << 16);
        a3 += __uint_as_float(cv.u.y & 0xffff0000u);
        a4 += __uint_as_float(cv.u.z << 16);
        a5 += __uint_as_float(cv.u.z & 0xffff0000u);
        a6 += __uint_as_float(cv.u.w << 16);
        a7 += __uint_as_float(cv.u.w & 0xffff0000u);
      };
      auto run_walk = [&](auto fetch) {
        for (int i = beg; i < endAll; i += 4) {
          const int nrem = endAll - i;
          short8 h0, h1, h2, h3;
          h0 = fetch(i);
          if (nrem > 1) h1 = fetch(i + 1);
          if (nrem > 2) h2 = fetch(i + 2);
          if (nrem > 3) h3 = fetch(i + 3);
          bump(i);      add8(h0);
          if (nrem > 1) { bump(i + 1); add8(h1); }
          if (nrem > 2) { bump(i + 2); add8(h2); }
          if (nrem > 3) { bump(i + 3); add8(h3); }
        }
        while (rl < rlB) { flush(); ++rl; }   // trailing (incl. empty) cells
      };

      if (endAll <= SPK_CAP) {
        run_walk([&](int i) {
          return *(const short8*)(hb + (size_t)spk[i] * DIM + mh8);
        });
      } else {   // overflow fallback (essentially never taken)
        run_walk([&](int i) {
          return *(const short8*)(hb + (size_t)es[e0 + i] * DIM + mh8);
        });
      }
    } else if (half == 0) {
      // self-loop mini-chunk: own row (feeds rel 20 = loop_w), slot 0
      short8 hv = *(const short8*)(hb + (size_t)(dst_base + g) * DIM + mh8);
      Sb8[g * 80 + (m ^ g)] = hv;   // already bf16; sum of one row
    }
    __syncthreads();

    // ---- phase 2: nc-split 8 ways. wave w owns cols [16w,16w+16) ----
    const int rc = (c == 4) ? 1 : 5;
    for (int rl2 = 0; rl2 < rc; ++rl2) {
      const int r = (c == 4) ? (NRELP - 1) : (c * 5 + rl2);
      const unsigned short* bp =
          WP + ((((size_t)(layer * NRELP + r) * 4) * 8 + w) * 64 + lane) * 8;
#pragma unroll
      for (int ks = 0; ks < 4; ++ks) {
        short8 a = Sb8[m * 80 + ((rl2 * 16 + ks * 4 + quad) ^ m)];
        short8 b = *(const short8*)(bp + (size_t)ks * 4096);
        acc = __builtin_amdgcn_mfma_f32_16x16x32_bf16(a, b, acc, 0, 0, 0);
      }
    }
    __syncthreads();
  }

  // ---- epilogue: wave w stores its 16-col tile; no cross-wave reduction ----
  const int col = w * 16 + m;
  const float bv = bias[col];
  if (outb) {
#pragma unroll
    for (int i = 0; i < 4; ++i)
      outb[(size_t)(dst_base + quad * 4 + i) * DIM + col] =
          f32_to_bf16_raw(acc[i] + bv);
  } else {
#pragma unroll
    for (int i = 0; i < 4; ++i)
      outf[(size_t)(dst_base + quad * 4 + i) * DIM + col] = acc[i] + bv;
  }
}

// ---------------- launch ----------------
extern "C" void kernel_launch(void* const* d_in, const int* in_sizes, int n_in,
                              void* d_out, int out_size, void* d_ws, size_t ws_size,
                              hipStream_t stream) {
  const float* h0     = (const float*)d_in[0];
  const float* W      = (const float*)d_in[1];
  const float* loop_w = (const float*)d_in[2];
  const float* bias   = (const float*)d_in[3];
  const int* esrc     = (const int*)d_in[4];
  const int* edst     = (const int*)d_in[5];
  const int* etyp     = (const int*)d_in[6];
  float* out = (float*)d_out;

  char* ws = (char*)d_ws;
  size_t off = 0;
  auto alloc = [&](size_t bytes) -> void* {
    void* p = ws + off;
    off = (off + bytes + 255) & ~(size_t)255;
    return p;
  };
  unsigned short* hb0   = (unsigned short*)alloc((size_t)NN * DIM * 2);   // 12.8 MB
  unsigned short* hb1   = (unsigned short*)alloc((size_t)NN * DIM * 2);   // 12.8 MB
  unsigned short* WP    = (unsigned short*)alloc((size_t)PACKED_ELEMS * 2);
  unsigned int*   tt    = (unsigned int*)alloc((size_t)(TT_N + 1) * 4);   // 2.5 MB
  unsigned int*   tts   = (unsigned int*)alloc((size_t)(TT_N + 1) * 4);   // 2.5 MB
  unsigned int*   btot  = (unsigned int*)alloc((size_t)NBLK_TT * 4);
  unsigned int*   ep    = (unsigned int*)alloc((size_t)NE * 4);           // 6.4 MB
  unsigned int*   cofs  = (unsigned int*)alloc((size_t)(CELLS + 1) * 4);  // 4 MB
  unsigned short* es    = (unsigned short*)alloc((size_t)NE * 2);         // 3.2 MB

  tile_count_kernel<<<CHB, 256, 0, stream>>>(edst, tt);
  scanA_kernel<<<NBLK_TT, 256, 0, stream>>>(tt, tts, btot, TT_N);
  scanB_kernel<<<1, 1024, 0, stream>>>(btot, tts, NBLK_TT, TT_N);
  scanC_kernel<<<NBLK_TT, 256, 0, stream>>>(btot, tts, TT_N);
  tile_scatter_kernel<<<CHB, 256, 0, stream>>>(esrc, edst, etyp, tts, ep);
  tile_sort_kernel<<<NTILE, 512, 0, stream>>>(ep, tts, es, cofs);

  pack_w_kernel<<<(PACKED_ELEMS + 255) / 256, 256, 0, stream>>>(W, loop_w, WP);
  cvt_bf16_kernel<<<(NN * DIM / 4 + 255) / 256, 256, 0, stream>>>(h0, hb0, NN * DIM / 4);

  rgcn_layer_kernel<<<NTILE, 512, 0, stream>>>(hb0, WP, bias, 0, cofs, es,
                                               nullptr, hb1);
  rgcn_layer_kernel<<<NTILE, 512, 0, stream>>>(hb1, WP, bias + DIM, 1, cofs, es,
                                               out, nullptr);
}